// Round 4
// baseline (209.305 us; speedup 1.0000x reference)
//
#include <hip/hip_runtime.h>
#include <math.h>

#define NN 2048
#define BB 4
#define HD 128
#define CNUM 8
#define WPB 4               // waves (= centers) per block in k_dist
#define PCHUNK 64           // nodes per block in k_pool1
#define NCHUNKS (NN / PCHUNK)

__device__ __forceinline__ void top3_insert(float sq, int j,
        float& s0, float& s1, float& s2, int& i0, int& i1, int& i2) {
    if (sq < s2) {                        // strict <: lower j wins ties (j increasing)
        if (sq < s1) {
            s2 = s1; i2 = i1;
            if (sq < s0) { s1 = s0; i1 = i0; s0 = sq; i0 = j; }
            else         { s1 = sq; i1 = j; }
        } else { s2 = sq; i2 = j; }
    }
}

// merge-insert with explicit (sq, j) lexicographic tie-break
__device__ __forceinline__ void top3_insert_lex(float sq, int j,
        float& s0, float& s1, float& s2, int& i0, int& i1, int& i2) {
    if (sq < s2 || (sq == s2 && j < i2)) {
        if (sq < s1 || (sq == s1 && j < i1)) {
            s2 = s1; i2 = i1;
            if (sq < s0 || (sq == s0 && j < i0)) { s1 = s0; i1 = i0; s0 = sq; i0 = j; }
            else                                 { s1 = sq; i1 = j; }
        } else { s2 = sq; i2 = j; }
    }
}

// K1 (fused): one wave per center. Lane l scans j = l, l+64, ... (coalesced
// ds_read_b128, no broadcast chain), per-lane top3+dsum, butterfly merge.
__global__ __launch_bounds__(256) void k_dist(
        const float* __restrict__ x,
        int* __restrict__ idx, float* __restrict__ vals,
        float* __restrict__ de, float* __restrict__ dv) {
    __shared__ float4 s4[NN];             // 32 KB: all nodes of this batch
    const int b = blockIdx.y;
    const float* xb = x + (size_t)b * NN * 3;
    for (int t = threadIdx.x; t < NN; t += 256) {
        float a = xb[3 * t], c = xb[3 * t + 1], d = xb[3 * t + 2];
        s4[t] = make_float4(a, c, d, a * a + c * c + d * d);
    }
    __syncthreads();
    const int wave = threadIdx.x >> 6;
    const int lane = threadIdx.x & 63;
    const int i = blockIdx.x * WPB + wave;          // this wave's center
    const float4 ci = s4[i];
    float s0 = INFINITY, s1 = INFINITY, s2 = INFINITY;
    int i0 = -1, i1 = -1, i2 = -1;
    float dsum = 0.f;
    #pragma unroll 4
    for (int t = lane; t < NN; t += 64) {           // 32 iters, coalesced LDS
        float4 p = s4[t];
        float sq = fmaxf(ci.w + p.w - 2.0f * (ci.x * p.x + ci.y * p.y + ci.z * p.z), 0.0f);
        dsum += sqrtf(sq + 1e-12f);
        top3_insert(sq, t, s0, s1, s2, i0, i1, i2);
    }
    // butterfly merge across the wave (all lanes converge to same result)
    for (int off = 32; off > 0; off >>= 1) {
        float o0 = __shfl_xor(s0, off), o1 = __shfl_xor(s1, off), o2 = __shfl_xor(s2, off);
        int   j0 = __shfl_xor(i0, off), j1 = __shfl_xor(i1, off), j2 = __shfl_xor(i2, off);
        dsum += __shfl_xor(dsum, off);
        top3_insert_lex(o0, j0, s0, s1, s2, i0, i1, i2);
        top3_insert_lex(o1, j1, s0, s1, s2, i0, i1, i2);
        top3_insert_lex(o2, j2, s0, s1, s2, i0, i1, i2);
    }
    if (lane == 0) {
        const float avg = dsum * (1.0f / NN);
        const float inva2 = 1.0f / (avg * avg);
        const float v0 = expf(-s0 * inva2);
        const float v1 = expf(-s1 * inva2);
        const float v2 = expf(-s2 * inva2);
        const int base = (b * NN + i) * 3;
        idx[base] = i0; idx[base + 1] = i1; idx[base + 2] = i2;
        vals[base] = v0; vals[base + 1] = v1; vals[base + 2] = v2;
        de[b * NN + i] = v0 + v1 + v2;
        atomicAdd(&dv[b * NN + i0], v0);
        atomicAdd(&dv[b * NN + i1], v1);
        atomicAdd(&dv[b * NN + i2], v2);
    }
}

// K2: first G-application on W1. 256-thread blocks, 2 edges per block.
__global__ void k_conv1(const float* __restrict__ W1, const int* __restrict__ idx,
                        const float* __restrict__ vals, const float* __restrict__ de,
                        const float* __restrict__ dv, float* __restrict__ Z1) {
    const int e = blockIdx.x * 2 + (threadIdx.x >> 7);
    const int b = blockIdx.y, h = threadIdx.x & (HD - 1);
    const int base = (b * NN + e) * 3;
    const int j0 = idx[base], j1 = idx[base + 1], j2 = idx[base + 2];
    const float v0 = vals[base], v1 = vals[base + 1], v2 = vals[base + 2];
    const float ide = 1.0f / de[b * NN + e];
    const float g0 = v0 * rsqrtf(dv[b * NN + j0]);
    const float g1 = v1 * rsqrtf(dv[b * NN + j1]);
    const float g2 = v2 * rsqrtf(dv[b * NN + j2]);
    const float y = ide * (g0 * W1[j0 * HD + h] + g1 * W1[j1 * HD + h] + g2 * W1[j2 * HD + h]);
    atomicAdd(&Z1[((size_t)(b * NN + j0)) * HD + h], v0 * y);
    atomicAdd(&Z1[((size_t)(b * NN + j1)) * HD + h], v1 * y);
    atomicAdd(&Z1[((size_t)(b * NN + j2)) * HD + h], v2 * y);
}

// K3: second G-application on f1 = dv2*Z1 + b1.
__global__ void k_conv2(const float* __restrict__ b1, const int* __restrict__ idx,
                        const float* __restrict__ vals, const float* __restrict__ de,
                        const float* __restrict__ dv, const float* __restrict__ Z1,
                        float* __restrict__ Z2) {
    const int e = blockIdx.x * 2 + (threadIdx.x >> 7);
    const int b = blockIdx.y, h = threadIdx.x & (HD - 1);
    const int base = (b * NN + e) * 3;
    const int j0 = idx[base], j1 = idx[base + 1], j2 = idx[base + 2];
    const float v0 = vals[base], v1 = vals[base + 1], v2 = vals[base + 2];
    const float ide = 1.0f / de[b * NN + e];
    const float bh = b1[h];
    const float d0 = rsqrtf(dv[b * NN + j0]);
    const float d1 = rsqrtf(dv[b * NN + j1]);
    const float d2 = rsqrtf(dv[b * NN + j2]);
    const float f0 = d0 * Z1[((size_t)(b * NN + j0)) * HD + h] + bh;
    const float f1 = d1 * Z1[((size_t)(b * NN + j1)) * HD + h] + bh;
    const float f2 = d2 * Z1[((size_t)(b * NN + j2)) * HD + h] + bh;
    const float y = ide * (v0 * d0 * f0 + v1 * d1 * f1 + v2 * d2 * f2);
    atomicAdd(&Z2[((size_t)(b * NN + j0)) * HD + h], v0 * y);
    atomicAdd(&Z2[((size_t)(b * NN + j1)) * HD + h], v1 * y);
    atomicAdd(&Z2[((size_t)(b * NN + j2)) * HD + h], v2 * y);
}

// K4a: partial max over 64-node chunks. grid (B, 32) x 128 threads.
__global__ void k_pool1(const float* __restrict__ dv, const float* __restrict__ Z2,
                        float* __restrict__ pmax) {
    const int b = blockIdx.x, ch = blockIdx.y, h = threadIdx.x;
    const int v0 = ch * PCHUNK;
    float mx = -INFINITY;
    for (int v = v0; v < v0 + PCHUNK; ++v) {
        const float d2 = rsqrtf(dv[b * NN + v]);
        mx = fmaxf(mx, d2 * Z2[((size_t)(b * NN + v)) * HD + h]);
    }
    pmax[(b * NCHUNKS + ch) * HD + h] = mx;
}

// K4b: merge partial maxes + classifier. grid B x 128 threads.
__global__ void k_pool2(const float* __restrict__ Wc, const float* __restrict__ bc,
                        const float* __restrict__ pmax, float* __restrict__ out) {
    __shared__ float smax[HD];
    const int b = blockIdx.x, h = threadIdx.x;
    float mx = -INFINITY;
    for (int c = 0; c < NCHUNKS; ++c)
        mx = fmaxf(mx, pmax[(b * NCHUNKS + c) * HD + h]);
    smax[h] = mx;
    __syncthreads();
    if (h < CNUM) {
        float acc = bc[h];
        for (int q = 0; q < HD; ++q) acc += smax[q] * Wc[q * CNUM + h];
        out[b * CNUM + h] = acc;
    }
}

extern "C" void kernel_launch(void* const* d_in, const int* in_sizes, int n_in,
                              void* d_out, int out_size, void* d_ws, size_t ws_size,
                              hipStream_t stream) {
    const float* x  = (const float*)d_in[0];   // [B,N,3]
    const float* W1 = (const float*)d_in[1];   // [N,H1]
    const float* b1 = (const float*)d_in[2];   // [H1]
    const float* Wc = (const float*)d_in[3];   // [H1,C]
    const float* bc = (const float*)d_in[4];   // [C]
    float* out = (float*)d_out;                // [B,C]

    float* ws = (float*)d_ws;
    float* dv   = ws;                                  // B*N           (zeroed)
    float* Z1   = dv + BB * NN;                        // B*N*HD        (zeroed)
    float* Z2   = Z1 + (size_t)BB * NN * HD;           // B*N*HD        (zeroed)
    float* vals = Z2 + (size_t)BB * NN * HD;           // B*N*3
    float* de   = vals + BB * NN * 3;                  // B*N
    int*   idx  = (int*)(de + BB * NN);                // B*N*3
    float* pmax = (float*)(idx + BB * NN * 3);         // B*32*HD

    // zero the contiguous [dv | Z1 | Z2] region
    hipMemsetAsync(dv, 0, (size_t)(BB * NN) * (1 + 2 * HD) * sizeof(float), stream);

    k_dist<<<dim3(NN / WPB, BB), 256, 0, stream>>>(x, idx, vals, de, dv);
    k_conv1<<<dim3(NN / 2, BB), 256, 0, stream>>>(W1, idx, vals, de, dv, Z1);
    k_conv2<<<dim3(NN / 2, BB), 256, 0, stream>>>(b1, idx, vals, de, dv, Z1, Z2);
    k_pool1<<<dim3(BB, NCHUNKS), HD, 0, stream>>>(dv, Z2, pmax);
    k_pool2<<<BB, HD, 0, stream>>>(Wc, bc, pmax, out);
}

// Round 5
// 208.471 us; speedup vs baseline: 1.0040x; 1.0040x over previous
//
#include <hip/hip_runtime.h>
#include <math.h>

#define NN 2048
#define BB 4
#define HD 128
#define CNUM 8
#define WPB 4               // waves (= centers) per block in k_dist
#define PCHUNK 64           // nodes per block in k_pool1
#define NCHUNKS (NN / PCHUNK)

__device__ __forceinline__ void top3_insert(float sq, int j,
        float& s0, float& s1, float& s2, int& i0, int& i1, int& i2) {
    if (sq < s2) {                        // strict <: lower j wins ties (j increasing)
        if (sq < s1) {
            s2 = s1; i2 = i1;
            if (sq < s0) { s1 = s0; i1 = i0; s0 = sq; i0 = j; }
            else         { s1 = sq; i1 = j; }
        } else { s2 = sq; i2 = j; }
    }
}

// merge-insert with explicit (sq, j) lexicographic tie-break
__device__ __forceinline__ void top3_insert_lex(float sq, int j,
        float& s0, float& s1, float& s2, int& i0, int& i1, int& i2) {
    if (sq < s2 || (sq == s2 && j < i2)) {
        if (sq < s1 || (sq == s1 && j < i1)) {
            s2 = s1; i2 = i1;
            if (sq < s0 || (sq == s0 && j < i0)) { s1 = s0; i1 = i0; s0 = sq; i0 = j; }
            else                                 { s1 = sq; i1 = j; }
        } else { s2 = sq; i2 = j; }
    }
}

// K1: one wave per center, lane-strided coalesced LDS reads, manual 4x unroll.
// __launch_bounds__(256, 2): VGPR budget up to 256/thread -- the previous
// rounds' inner loops were scratch-spilling (VGPR_Count 12/44/52 with 15-40
// live values; WRITE_SIZE 7-28x logical output; ~1000 cyc/iter stalls).
__global__ __launch_bounds__(256, 2) void k_dist(
        const float* __restrict__ x,
        int* __restrict__ idx, float* __restrict__ vals,
        float* __restrict__ de, float* __restrict__ dv) {
    __shared__ float4 s4[NN];             // 32 KB: all nodes of this batch
    const int b = blockIdx.y;
    const float* xb = x + (size_t)b * NN * 3;
    for (int t = threadIdx.x; t < NN; t += 256) {
        float a = xb[3 * t], c = xb[3 * t + 1], d = xb[3 * t + 2];
        s4[t] = make_float4(a, c, d, a * a + c * c + d * d);
    }
    __syncthreads();
    const int wave = threadIdx.x >> 6;
    const int lane = threadIdx.x & 63;
    const int i = blockIdx.x * WPB + wave;          // this wave's center
    const float4 ci = s4[i];
    float s0 = INFINITY, s1 = INFINITY, s2 = INFINITY;
    int i0 = -1, i1 = -1, i2 = -1;
    float dsA = 0.f, dsB = 0.f;
    for (int t = lane; t < NN; t += 256) {          // 8 iterations, 4 elems each
        const float4 pa = s4[t];
        const float4 pb = s4[t + 64];
        const float4 pc = s4[t + 128];
        const float4 pd = s4[t + 192];
        const float qa = fmaxf(ci.w + pa.w - 2.0f * (ci.x * pa.x + ci.y * pa.y + ci.z * pa.z), 0.0f);
        const float qb = fmaxf(ci.w + pb.w - 2.0f * (ci.x * pb.x + ci.y * pb.y + ci.z * pb.z), 0.0f);
        const float qc = fmaxf(ci.w + pc.w - 2.0f * (ci.x * pc.x + ci.y * pc.y + ci.z * pc.z), 0.0f);
        const float qd = fmaxf(ci.w + pd.w - 2.0f * (ci.x * pd.x + ci.y * pd.y + ci.z * pd.z), 0.0f);
        dsA += sqrtf(qa + 1e-12f) + sqrtf(qc + 1e-12f);
        dsB += sqrtf(qb + 1e-12f) + sqrtf(qd + 1e-12f);
        top3_insert(qa, t,       s0, s1, s2, i0, i1, i2);
        top3_insert(qb, t + 64,  s0, s1, s2, i0, i1, i2);
        top3_insert(qc, t + 128, s0, s1, s2, i0, i1, i2);
        top3_insert(qd, t + 192, s0, s1, s2, i0, i1, i2);
    }
    float dsum = dsA + dsB;
    // butterfly merge across the wave (all lanes converge to same result)
    for (int off = 32; off > 0; off >>= 1) {
        float o0 = __shfl_xor(s0, off), o1 = __shfl_xor(s1, off), o2 = __shfl_xor(s2, off);
        int   j0 = __shfl_xor(i0, off), j1 = __shfl_xor(i1, off), j2 = __shfl_xor(i2, off);
        dsum += __shfl_xor(dsum, off);
        top3_insert_lex(o0, j0, s0, s1, s2, i0, i1, i2);
        top3_insert_lex(o1, j1, s0, s1, s2, i0, i1, i2);
        top3_insert_lex(o2, j2, s0, s1, s2, i0, i1, i2);
    }
    if (lane == 0) {
        const float avg = dsum * (1.0f / NN);
        const float inva2 = 1.0f / (avg * avg);
        const float v0 = expf(-s0 * inva2);
        const float v1 = expf(-s1 * inva2);
        const float v2 = expf(-s2 * inva2);
        const int base = (b * NN + i) * 3;
        idx[base] = i0; idx[base + 1] = i1; idx[base + 2] = i2;
        vals[base] = v0; vals[base + 1] = v1; vals[base + 2] = v2;
        de[b * NN + i] = v0 + v1 + v2;
        atomicAdd(&dv[b * NN + i0], v0);
        atomicAdd(&dv[b * NN + i1], v1);
        atomicAdd(&dv[b * NN + i2], v2);
    }
}

// K2: first G-application on W1. 256-thread blocks, 2 edges per block.
__global__ void k_conv1(const float* __restrict__ W1, const int* __restrict__ idx,
                        const float* __restrict__ vals, const float* __restrict__ de,
                        const float* __restrict__ dv, float* __restrict__ Z1) {
    const int e = blockIdx.x * 2 + (threadIdx.x >> 7);
    const int b = blockIdx.y, h = threadIdx.x & (HD - 1);
    const int base = (b * NN + e) * 3;
    const int j0 = idx[base], j1 = idx[base + 1], j2 = idx[base + 2];
    const float v0 = vals[base], v1 = vals[base + 1], v2 = vals[base + 2];
    const float ide = 1.0f / de[b * NN + e];
    const float g0 = v0 * rsqrtf(dv[b * NN + j0]);
    const float g1 = v1 * rsqrtf(dv[b * NN + j1]);
    const float g2 = v2 * rsqrtf(dv[b * NN + j2]);
    const float y = ide * (g0 * W1[j0 * HD + h] + g1 * W1[j1 * HD + h] + g2 * W1[j2 * HD + h]);
    atomicAdd(&Z1[((size_t)(b * NN + j0)) * HD + h], v0 * y);
    atomicAdd(&Z1[((size_t)(b * NN + j1)) * HD + h], v1 * y);
    atomicAdd(&Z1[((size_t)(b * NN + j2)) * HD + h], v2 * y);
}

// K3: second G-application on f1 = dv2*Z1 + b1.
__global__ void k_conv2(const float* __restrict__ b1, const int* __restrict__ idx,
                        const float* __restrict__ vals, const float* __restrict__ de,
                        const float* __restrict__ dv, const float* __restrict__ Z1,
                        float* __restrict__ Z2) {
    const int e = blockIdx.x * 2 + (threadIdx.x >> 7);
    const int b = blockIdx.y, h = threadIdx.x & (HD - 1);
    const int base = (b * NN + e) * 3;
    const int j0 = idx[base], j1 = idx[base + 1], j2 = idx[base + 2];
    const float v0 = vals[base], v1 = vals[base + 1], v2 = vals[base + 2];
    const float ide = 1.0f / de[b * NN + e];
    const float bh = b1[h];
    const float d0 = rsqrtf(dv[b * NN + j0]);
    const float d1 = rsqrtf(dv[b * NN + j1]);
    const float d2 = rsqrtf(dv[b * NN + j2]);
    const float f0 = d0 * Z1[((size_t)(b * NN + j0)) * HD + h] + bh;
    const float f1 = d1 * Z1[((size_t)(b * NN + j1)) * HD + h] + bh;
    const float f2 = d2 * Z1[((size_t)(b * NN + j2)) * HD + h] + bh;
    const float y = ide * (v0 * d0 * f0 + v1 * d1 * f1 + v2 * d2 * f2);
    atomicAdd(&Z2[((size_t)(b * NN + j0)) * HD + h], v0 * y);
    atomicAdd(&Z2[((size_t)(b * NN + j1)) * HD + h], v1 * y);
    atomicAdd(&Z2[((size_t)(b * NN + j2)) * HD + h], v2 * y);
}

// K4a: partial max over 64-node chunks. grid (B, 32) x 128 threads.
__global__ void k_pool1(const float* __restrict__ dv, const float* __restrict__ Z2,
                        float* __restrict__ pmax) {
    const int b = blockIdx.x, ch = blockIdx.y, h = threadIdx.x;
    const int v0 = ch * PCHUNK;
    float mx = -INFINITY;
    for (int v = v0; v < v0 + PCHUNK; ++v) {
        const float d2 = rsqrtf(dv[b * NN + v]);
        mx = fmaxf(mx, d2 * Z2[((size_t)(b * NN + v)) * HD + h]);
    }
    pmax[(b * NCHUNKS + ch) * HD + h] = mx;
}

// K4b: merge partial maxes + classifier. grid B x 128 threads.
__global__ void k_pool2(const float* __restrict__ Wc, const float* __restrict__ bc,
                        const float* __restrict__ pmax, float* __restrict__ out) {
    __shared__ float smax[HD];
    const int b = blockIdx.x, h = threadIdx.x;
    float mx = -INFINITY;
    for (int c = 0; c < NCHUNKS; ++c)
        mx = fmaxf(mx, pmax[(b * NCHUNKS + c) * HD + h]);
    smax[h] = mx;
    __syncthreads();
    if (h < CNUM) {
        float acc = bc[h];
        for (int q = 0; q < HD; ++q) acc += smax[q] * Wc[q * CNUM + h];
        out[b * CNUM + h] = acc;
    }
}

extern "C" void kernel_launch(void* const* d_in, const int* in_sizes, int n_in,
                              void* d_out, int out_size, void* d_ws, size_t ws_size,
                              hipStream_t stream) {
    const float* x  = (const float*)d_in[0];   // [B,N,3]
    const float* W1 = (const float*)d_in[1];   // [N,H1]
    const float* b1 = (const float*)d_in[2];   // [H1]
    const float* Wc = (const float*)d_in[3];   // [H1,C]
    const float* bc = (const float*)d_in[4];   // [C]
    float* out = (float*)d_out;                // [B,C]

    float* ws = (float*)d_ws;
    float* dv   = ws;                                  // B*N           (zeroed)
    float* Z1   = dv + BB * NN;                        // B*N*HD        (zeroed)
    float* Z2   = Z1 + (size_t)BB * NN * HD;           // B*N*HD        (zeroed)
    float* vals = Z2 + (size_t)BB * NN * HD;           // B*N*3
    float* de   = vals + BB * NN * 3;                  // B*N
    int*   idx  = (int*)(de + BB * NN);                // B*N*3
    float* pmax = (float*)(idx + BB * NN * 3);         // B*32*HD

    // zero the contiguous [dv | Z1 | Z2] region
    hipMemsetAsync(dv, 0, (size_t)(BB * NN) * (1 + 2 * HD) * sizeof(float), stream);

    k_dist<<<dim3(NN / WPB, BB), 256, 0, stream>>>(x, idx, vals, de, dv);
    k_conv1<<<dim3(NN / 2, BB), 256, 0, stream>>>(W1, idx, vals, de, dv, Z1);
    k_conv2<<<dim3(NN / 2, BB), 256, 0, stream>>>(b1, idx, vals, de, dv, Z1, Z2);
    k_pool1<<<dim3(BB, NCHUNKS), HD, 0, stream>>>(dv, Z2, pmax);
    k_pool2<<<BB, HD, 0, stream>>>(Wc, bc, pmax, out);
}